// Round 8
// baseline (220.934 us; speedup 1.0000x reference)
//
#include <hip/hip_runtime.h>
#include <cstddef>

#define B_  16
#define C_  512
#define N_  1024

typedef __attribute__((ext_vector_type(8))) __bf16 bf16x8;
typedef __attribute__((ext_vector_type(4))) float f32x4;
typedef __attribute__((ext_vector_type(4))) short s16x4;

__device__ __forceinline__ unsigned short f2bf(float x) {
  unsigned u = __float_as_uint(x);
  return (unsigned short)((u + 0x7fffu + ((u >> 16) & 1u)) >> 16);
}
__device__ __forceinline__ float bf2f(unsigned short h) {
  return __uint_as_float(((unsigned)h) << 16);
}

#define GLDS16(g, l)                                                            \
  __builtin_amdgcn_global_load_lds(                                             \
      (const __attribute__((address_space(1))) void*)(g),                       \
      (__attribute__((address_space(3))) void*)(l), 16, 0, 0)

// ---------- weight fp32 -> bf16 ----------
__global__ __launch_bounds__(256) void wconv_kernel(
    const float* __restrict__ wq, const float* __restrict__ wp,
    unsigned short* __restrict__ oq, unsigned short* __restrict__ op) {
  int i = blockIdx.x * 256 + threadIdx.x;  // float4 chunks
  const float4* src; unsigned short* dst; int off;
  if (i < 196608) { src = (const float4*)wq; dst = oq; off = i; }
  else            { src = (const float4*)wp; dst = op; off = i - 196608; }
  float4 v = src[off];
  union { unsigned short s[4]; ushort4 u; } o;
  o.s[0] = f2bf(v.x); o.s[1] = f2bf(v.y);
  o.s[2] = f2bf(v.z); o.s[3] = f2bf(v.w);
  *(ushort4*)(dst + (size_t)off * 4) = o.u;
}

// ---------- GroupNorm: writes hT[b][n][c] bf16 ----------
__global__ __launch_bounds__(256) void gn_kernel(
    const float* __restrict__ x, const float* __restrict__ gamma,
    const float* __restrict__ beta, unsigned short* __restrict__ hT) {
  int bg = blockIdx.x;
  int b = bg >> 5, g = bg & 31;
  size_t base = ((size_t)b * C_ + (size_t)g * 16) * N_;
  const float4* x4 = (const float4*)(x + base);
  int tid = threadIdx.x;

  float sum = 0.f, sq = 0.f;
  float4 vv[16];
#pragma unroll
  for (int i = 0; i < 16; i++) {
    float4 v = x4[tid + i * 256];
    vv[i] = v;
    sum += v.x + v.y + v.z + v.w;
    sq  += v.x * v.x + v.y * v.y + v.z * v.z + v.w * v.w;
  }
#pragma unroll
  for (int off = 32; off > 0; off >>= 1) {
    sum += __shfl_down(sum, off, 64);
    sq  += __shfl_down(sq, off, 64);
  }
  __shared__ float sm[4], sv[4];
  int lane = tid & 63, w = tid >> 6;
  if (lane == 0) { sm[w] = sum; sv[w] = sq; }
  __syncthreads();
  if (tid == 0) {
    float s = sm[0] + sm[1] + sm[2] + sm[3];
    float q = sv[0] + sv[1] + sv[2] + sv[3];
    float mean = s * (1.f / 16384.f);
    float var  = q * (1.f / 16384.f) - mean * mean;
    sm[0] = mean;
    sv[0] = rsqrtf(var + 1e-5f);
  }
  __syncthreads();
  float mean = sm[0], rstd = sv[0];

  union { unsigned short s[16]; uint4 u[2]; } row[4];
#pragma unroll
  for (int i = 0; i < 16; i++) {
    int c = g * 16 + i;
    float ga = gamma[c] * rstd;
    float be = beta[c] - mean * ga;
    float4 v = vv[i];
    row[0].s[i] = f2bf(v.x * ga + be);
    row[1].s[i] = f2bf(v.y * ga + be);
    row[2].s[i] = f2bf(v.z * ga + be);
    row[3].s[i] = f2bf(v.w * ga + be);
  }
#pragma unroll
  for (int j = 0; j < 4; j++) {
    uint4* dst = (uint4*)(hT + ((size_t)b * N_ + 4 * tid + j) * C_ + g * 16);
    dst[0] = row[j].u[0];
    dst[1] = row[j].u[1];
  }
}

// ---------- MFMA GEMM: Out[b,m,n] = sum_k W[m,k]*InT[b,n,k] + bias[m] (+resid) ----------
// K-loop is DOUBLE-BUFFERED: tile k+1's global_load_lds are issued before
// computing tile k, so the ~600-900cy load latency hides under the MFMA +
// ds_read phase (round-5 counters: the old load->drain->compute structure ran
// the GEMMs at ~250 TF with full latency exposed every iteration).
// OUT_BF16==1 (QKV): K rows (m in [512,1024)) are written TRANSPOSED into the
// K region as KT[b][n][m-512], via an LDS staging buffer (rows padded to 136
// shorts) so the global writes are 256B contiguous per n.
template <int OUT_BF16>
__global__ __launch_bounds__(256) void gemm_mfma(
    const unsigned short* __restrict__ Wb, const float* __restrict__ bias,
    const unsigned short* __restrict__ InT, const float* __restrict__ resid,
    void* __restrict__ Out, int M) {
  // planes: A buffers = SH[0],SH[1]; B buffers = SH[2],SH[3]; epi aliases all
  __shared__ __align__(16) unsigned short SH[4][128 * 34];

  const int b = blockIdx.z;
  const int n0 = blockIdx.x * 128, m0 = blockIdx.y * 128;
  const int tid = threadIdx.x;
  const int lane = tid & 63, wave = tid >> 6;
  const int col = lane & 15, quad = lane >> 4;
  const int wm = (wave >> 1) << 6, wn = (wave & 1) << 6;

  const unsigned short* Ag = Wb + (size_t)m0 * C_;
  const unsigned short* Bg = InT + ((size_t)b * N_ + n0) * C_;

  const int r0 = tid >> 2, c0 = (tid & 3) << 3;

  f32x4 acc[4][4];
#pragma unroll
  for (int i = 0; i < 4; i++)
#pragma unroll
    for (int j = 0; j < 4; j++) acc[i][j] = f32x4{0.f, 0.f, 0.f, 0.f};

  // stage K-tile 0 into buffer 0
  GLDS16(Ag + (size_t)r0 * C_ + c0,        &SH[0][tid * 8]);
  GLDS16(Ag + (size_t)(r0 + 64) * C_ + c0, &SH[0][(tid + 256) * 8]);
  GLDS16(Bg + (size_t)r0 * C_ + c0,        &SH[2][tid * 8]);
  GLDS16(Bg + (size_t)(r0 + 64) * C_ + c0, &SH[2][(tid + 256) * 8]);
  __syncthreads();

  for (int it = 0; it < 16; it++) {
    const int cur = it & 1;
    if (it < 15) {  // prefetch next K-tile into the other buffer
      const int k1 = (it + 1) * 32;
      GLDS16(Ag + (size_t)r0 * C_ + k1 + c0,        &SH[cur ^ 1][tid * 8]);
      GLDS16(Ag + (size_t)(r0 + 64) * C_ + k1 + c0, &SH[cur ^ 1][(tid + 256) * 8]);
      GLDS16(Bg + (size_t)r0 * C_ + k1 + c0,        &SH[2 + (cur ^ 1)][tid * 8]);
      GLDS16(Bg + (size_t)(r0 + 64) * C_ + k1 + c0, &SH[2 + (cur ^ 1)][(tid + 256) * 8]);
    }

    bf16x8 af[4], bfr[4];
#pragma unroll
    for (int mt = 0; mt < 4; mt++)
      af[mt] = *(const bf16x8*)&SH[cur][(wm + mt * 16 + col) * 32 + quad * 8];
#pragma unroll
    for (int nt = 0; nt < 4; nt++)
      bfr[nt] = *(const bf16x8*)&SH[2 + cur][(wn + nt * 16 + col) * 32 + quad * 8];
#pragma unroll
    for (int mt = 0; mt < 4; mt++)
#pragma unroll
      for (int nt = 0; nt < 4; nt++)
        acc[mt][nt] = __builtin_amdgcn_mfma_f32_16x16x32_bf16(
            af[mt], bfr[nt], acc[mt][nt], 0, 0, 0);

    if (it < 15) __syncthreads();  // drains prefetch (vmcnt0) + read/write fence
  }

  const bool kT = OUT_BF16 && (m0 >= 512) && (m0 < 1024);

  if (kT) {
    // Transposed K output via LDS: epi[64 n][136 shorts] per n-half.
    unsigned short* epi = &SH[0][0];
    unsigned short* kt_out =
        (unsigned short*)Out + ((size_t)b * 1536 + 512) * N_ + (m0 - 512);
#pragma unroll
    for (int hf = 0; hf < 2; hf++) {
      __syncthreads();
      if ((wave & 1) == hf) {
#pragma unroll
        for (int mt = 0; mt < 4; mt++) {
          int mloc = wm + mt * 16 + quad * 4;      // 0..127 within block tile
          int mabs = m0 + mloc;
#pragma unroll
          for (int nt = 0; nt < 4; nt++) {
            union { unsigned short s[4]; ushort4 v; } o;
#pragma unroll
            for (int r = 0; r < 4; r++)
              o.s[r] = f2bf(acc[mt][nt][r] + bias[mabs + r]);
            *(ushort4*)&epi[(nt * 16 + col) * 136 + mloc] = o.v;
          }
        }
      }
      __syncthreads();
#pragma unroll
      for (int pass = 0; pass < 4; pass++) {
        int n_l = (tid >> 4) + pass * 16;
        int ch = tid & 15;
        uint4 v = *(const uint4*)&epi[n_l * 136 + ch * 8];
        *(uint4*)(kt_out + (size_t)(n0 + hf * 64 + n_l) * 512 + ch * 8) = v;
      }
    }
    return;
  }

#pragma unroll
  for (int mt = 0; mt < 4; mt++) {
    int mbase = m0 + wm + mt * 16 + quad * 4;
#pragma unroll
    for (int nt = 0; nt < 4; nt++) {
      int n = n0 + wn + nt * 16 + col;
      if constexpr (OUT_BF16) {
#pragma unroll
        for (int r = 0; r < 4; r++) {
          float v = acc[mt][nt][r] + bias[mbase + r];
          ((unsigned short*)Out)[((size_t)b * M + mbase + r) * N_ + n] = f2bf(v);
        }
      } else {
#pragma unroll
        for (int r = 0; r < 4; r++) {
          int m = mbase + r;
          float v = acc[mt][nt][r] + bias[m];
          size_t off = ((size_t)b * M + m) * N_ + n;
          ((float*)Out)[off] = v + resid[off];
        }
      }
    }
  }
}

// ---------- MFMA flash attention, no-max softmax ----------
// global_load_lds staging + source-side XOR chunk swizzle (round-2 body),
// q-split grid: 1024 blocks (8 q-blocks x 16 b x 8 h), each wave owns 32 q
// rows (nt=2). bi&7 == head keeps all 8 q-blocks of one (b,h) on one XCD.
// __launch_bounds__(256,2): (256,4) forced the 64-VGPR tier and spilled ~80
// regs of state to scratch (rounds 3+4, +126MB HBM traffic); 116 VGPR still
// allows 4 waves/SIMD (<128 cliff), so 4 blocks/CU co-resident at runtime.
__device__ __forceinline__ void attn_tile(const bf16x8 (&qf)[2][2],
                                          const bf16x8 (&kf)[4][2],
                                          const s16x4 (&vf)[4][4],
                                          f32x4 (&O)[4][2], float (&l_i)[2]) {
#pragma unroll
  for (int nt = 0; nt < 2; nt++) {
    f32x4 sf[4];
#pragma unroll
    for (int mt = 0; mt < 4; mt++) sf[mt] = f32x4{0.f, 0.f, 0.f, 0.f};
    __builtin_amdgcn_s_setprio(1);
#pragma unroll
    for (int ks = 0; ks < 2; ks++)
#pragma unroll
      for (int mt = 0; mt < 4; mt++)
        sf[mt] = __builtin_amdgcn_mfma_f32_16x16x32_bf16(
            kf[mt][ks], qf[nt][ks], sf[mt], 0, 0, 0);
    __builtin_amdgcn_s_setprio(0);

    // p = exp(s); pack to bf16 by truncation (1 v_perm per pair)
    s16x4 pb[4];
    float lsum = 0.f;
#pragma unroll
    for (int kc = 0; kc < 4; kc++) {
      float e0 = __expf(sf[kc][0]);
      float e1 = __expf(sf[kc][1]);
      float e2 = __expf(sf[kc][2]);
      float e3 = __expf(sf[kc][3]);
      lsum += (e0 + e1) + (e2 + e3);
      unsigned lo = __builtin_amdgcn_perm(__float_as_uint(e1), __float_as_uint(e0), 0x07060302u);
      unsigned hi = __builtin_amdgcn_perm(__float_as_uint(e3), __float_as_uint(e2), 0x07060302u);
      union { unsigned u[2]; s16x4 v; } t;
      t.u[0] = lo; t.u[1] = hi;
      pb[kc] = t.v;
    }
    l_i[nt] += lsum;

    __builtin_amdgcn_s_setprio(1);
#pragma unroll
    for (int kc = 0; kc < 4; kc++)
#pragma unroll
      for (int mt = 0; mt < 4; mt++)
        O[mt][nt] = __builtin_amdgcn_mfma_f32_16x16x16bf16_1k(
            vf[mt][kc], pb[kc], O[mt][nt], 0, 0, 0);
    __builtin_amdgcn_s_setprio(0);
  }
}

__global__ __launch_bounds__(256, 2) void attn_mfma(
    const unsigned short* __restrict__ qkv, unsigned short* __restrict__ aoT) {
  __shared__ __align__(16) unsigned short KtL[2][64 * 64];
  __shared__ __align__(16) unsigned short VsL[2][64 * 64];

  const int tid = threadIdx.x;
  const int wave = tid >> 6, lane = tid & 63;
  const int quad = lane >> 4, col = lane & 15;
  const int bi = blockIdx.x;
  const int hh = bi & 7, b = (bi >> 3) & 15, qb = bi >> 7;  // bi%8==head -> XCD-grouped
  const int qblk = qb * 128 + wave * 32;

  const unsigned short* qp  = qkv + ((size_t)b * 1536 + hh * 64) * N_;           // [d][N]
  const unsigned short* ktp = qkv + ((size_t)b * 1536 + 512) * N_ + hh * 64;     // [key][512]
  const unsigned short* vp  = qkv + ((size_t)b * 1536 + 1024 + hh * 64) * N_;    // [d][N]

  // staging decomposition: row within half-tile + swizzled 16B chunk
  const int sr = tid >> 3;                          // 0..31
  const int sw8 = (((tid & 7) ^ (sr & 7)) << 3);    // swizzled chunk, in shorts

  // Q B-fragments pre-scaled by 0.125 (exact: exponent shift under RNE).
  bf16x8 qf[2][2];
#pragma unroll
  for (int nt = 0; nt < 2; nt++) {
    int qg = qblk + nt * 16 + col;
#pragma unroll
    for (int ks = 0; ks < 2; ks++) {
      union { unsigned short s[8]; bf16x8 v; } t;
#pragma unroll
      for (int j = 0; j < 8; j++) {
        int d = ks * 32 + quad * 8 + j;
        t.s[j] = f2bf(0.125f * bf2f(qp[(size_t)d * N_ + qg]));
      }
      qf[nt][ks] = t.v;
    }
  }

  float l_i[2];
  f32x4 O[4][2];
#pragma unroll
  for (int nt = 0; nt < 2; nt++) {
    l_i[nt] = 0.f;
#pragma unroll
    for (int mt = 0; mt < 4; mt++) O[mt][nt] = f32x4{0.f, 0.f, 0.f, 0.f};
  }

  // stage tile 0
  {
    const unsigned short* kq = ktp + (size_t)sr * 512 + sw8;
    GLDS16(kq,                    &KtL[0][tid * 8]);
    GLDS16(kq + (size_t)32 * 512, &KtL[0][(256 + tid) * 8]);
    const unsigned short* vq = vp + (size_t)sr * N_ + sw8;
    GLDS16(vq,                    &VsL[0][tid * 8]);
    GLDS16(vq + (size_t)32 * N_,  &VsL[0][(256 + tid) * 8]);
  }
  __syncthreads();

  for (int kt = 0; kt < 16; kt++) {
    const int cur = kt & 1;
    if (kt < 15) {
      const unsigned short* kq = ktp + (size_t)((kt + 1) * 64 + sr) * 512 + sw8;
      GLDS16(kq,                    &KtL[cur ^ 1][tid * 8]);
      GLDS16(kq + (size_t)32 * 512, &KtL[cur ^ 1][(256 + tid) * 8]);
      const unsigned short* vq = vp + (size_t)sr * N_ + (kt + 1) * 64 + sw8;
      GLDS16(vq,                    &VsL[cur ^ 1][tid * 8]);
      GLDS16(vq + (size_t)32 * N_,  &VsL[cur ^ 1][(256 + tid) * 8]);
    }

    // K A-fragments (16x16x32): b128, swizzle-matched
    bf16x8 kf[4][2];
#pragma unroll
    for (int mt = 0; mt < 4; mt++) {
      int key = 16 * mt + col;
#pragma unroll
      for (int ks = 0; ks < 2; ks++)
        kf[mt][ks] = *(const bf16x8*)
            &KtL[cur][key * 64 + (((ks * 4 + quad) ^ (col & 7)) << 3)];
    }
    // V A-fragments (16x16x16): b64, swizzle-matched at 8B granularity
    s16x4 vf[4][4];
#pragma unroll
    for (int mt = 0; mt < 4; mt++) {
      int d = 16 * mt + col;
#pragma unroll
      for (int kc = 0; kc < 4; kc++)
        vf[mt][kc] = *(const s16x4*)
            &VsL[cur][d * 64 + (((kc * 4 + quad) ^ ((col & 7) << 1)) << 2)];
    }

    attn_tile(qf, kf, vf, O, l_i);

    if (kt < 15) __syncthreads();
  }

#pragma unroll
  for (int nt = 0; nt < 2; nt++) {
    float ls = l_i[nt];
    ls += __shfl_xor(ls, 16, 64);
    ls += __shfl_xor(ls, 32, 64);
    float inv = 1.f / ls;
    int qg = qblk + nt * 16 + col;
    unsigned short* dst = aoT + ((size_t)b * N_ + qg) * C_ + hh * 64;
#pragma unroll
    for (int mt = 0; mt < 4; mt++) {
      union { unsigned short s[4]; ushort4 v; } o;
#pragma unroll
      for (int r = 0; r < 4; r++) o.s[r] = f2bf(O[mt][nt][r] * inv);
      *(ushort4*)(dst + mt * 16 + quad * 4) = o.v;
    }
  }
}

extern "C" void kernel_launch(void* const* d_in, const int* in_sizes, int n_in,
                              void* d_out, int out_size, void* d_ws, size_t ws_size,
                              hipStream_t stream) {
  (void)in_sizes; (void)n_in; (void)out_size; (void)ws_size;
  const float* x      = (const float*)d_in[0];
  const float* gamma  = (const float*)d_in[1];
  const float* beta   = (const float*)d_in[2];
  const float* w_qkv  = (const float*)d_in[3];
  const float* b_qkv  = (const float*)d_in[4];
  const float* w_proj = (const float*)d_in[5];
  const float* b_proj = (const float*)d_in[6];
  float* out = (float*)d_out;

  unsigned short* hT   = (unsigned short*)d_ws;                 // B*N*C bf16
  unsigned short* qkvb = hT + (size_t)B_ * N_ * C_;             // B*3C*N bf16 (K region = KT[b][n][512])
  unsigned short* aoT  = hT;                                    // reuse
  unsigned short* wqb  = qkvb + (size_t)B_ * 1536 * N_;         // 3C*C bf16
  unsigned short* wpb  = wqb + (size_t)1536 * 512;              // C*C bf16

  wconv_kernel<<<dim3(1024), dim3(256), 0, stream>>>(w_qkv, w_proj, wqb, wpb);
  gn_kernel<<<dim3(B_ * 32), dim3(256), 0, stream>>>(x, gamma, beta, hT);
  gemm_mfma<1><<<dim3(8, 12, 16), dim3(256), 0, stream>>>(
      wqb, b_qkv, hT, (const float*)nullptr, (void*)qkvb, 1536);
  attn_mfma<<<dim3(1024), dim3(256), 0, stream>>>(qkvb, aoT);
  gemm_mfma<0><<<dim3(8, 4, 16), dim3(256), 0, stream>>>(
      wpb, b_proj, aoT, x, (void*)out, 512);
}